// Round 10
// baseline (214.229 us; speedup 1.0000x reference)
//
#include <hip/hip_runtime.h>

// ARIMA(2,1,2) residual recurrence — page-burst memory pattern (R8) with
// proper parallelism (2 waves/block, 6 waves/CU, short predicated chains).
//
// eps_j = (y[j+3]-y[j+2]-mu-phi0*y[j+2]-phi1*y[j+1]) - q0*eps_{j-1} - q1*eps_{j-2}
// out[b,0..4092] = eps, out[b,4093..4094] = 0.
//
// R10 theory: all plateau kernels (R2/R5/R6/R7, ~3.9 TB/s) use 64-col tiles
// = 256B per DRAM page visit at 16KB stride. R8 fixed burst length (traffic
// 90+135MB, cleanest of session) but ran 4 waves/CU with a 128-step serial
// chain -> latency-starved (0.57 TB/s). This kernel keeps R8's >=1KB
// sequential runs per row AND R2-level residency:
//   block = 128 thr (2 waves) = 32 rows x one 256-out chunk
//   stage: 3x512B contiguous insts per row; dump: 2x512B (1KB run) per row
//   compute: lane=(row, 64-out sub-chunk), warm-up 61 from staged tile,
//   eps in-place over y[j+3]; barrier every 32 steps bounds cross-wave skew
//   (32) below the 64-col WAR hazard distance.
// LDS [360][33] col-major: all phases <=2-way banks. 47.5KB -> 3 blocks/CU.

#define TSEQ   4096
#define TOUT   4095
#define NJ     4093
#define CHUNK  256
#define NCHUNK 16
#define ROWS   32
#define RP     33     // row pitch (32 rows + 1)
#define TC     360    // col capacity (324 staged + junk-read slack)

__global__ __launch_bounds__(128) void arima_eps_burst(
    const float* __restrict__ y,
    const float* __restrict__ phi,
    const float* __restrict__ theta,
    const float* __restrict__ mu,
    float* __restrict__ out)
{
    __shared__ float tl[TC][RP];        // y tile (eps written in place)

    const int tid = threadIdx.x;        // 0..127
    const int g = blockIdx.x >> 4;      // 32-row group
    const int c = blockIdx.x & (NCHUNK - 1);
    const int rowbase = g * ROWS;

    const float p0 = phi[0], p1v = phi[1];
    const float q0 = theta[0], q1 = theta[1];
    const float m  = mu[0];
    const float c1 = 1.0f + p0;         // tg = y[j+3]-c1*y[j+2]-p1*y[j+1]-m

    const float* __restrict__ Y = y + (size_t)rowbase * TSEQ;
    float* __restrict__ O       = out + (size_t)rowbase * TOUT;

    const int j0 = c * CHUNK;
    const int j1 = min(j0 + CHUNK, NJ);
    const int tbase = max(j0 - 64, 0);          // staged window start
    const int ncols = min(TSEQ - tbase, 324);   // 324 (c<15) or 320 (c==15)

    // ---- stage: per row, 3 consecutive 512B coalesced loads ----
    #pragma unroll 4
    for (int r = 0; r < ROWS; ++r) {
        const float* rp = Y + (size_t)r * TSEQ + tbase;
        #pragma unroll
        for (int b = 0; b < 3; ++b) {
            const int idx = b * 128 + tid;
            if (idx < ncols) tl[idx][r] = rp[idx];
        }
    }
    __syncthreads();

    // ---- recurrence: lane -> (row r, sub-chunk s of 64 outputs) ----
    const int r = tid & 31;
    const int s = tid >> 5;                     // 0..3
    const int jsub   = j0 + 64 * s;             // outputs [jsub, jmax)
    const int jmax   = min(jsub + 64, j1);
    const int jstart = max(jsub - 61, 0);       // 61-step warm-up
    const int base   = jstart - tbase;          // tile col of y[jstart]

    float yp2 = tl[base + 1][r];                // y[jstart+1]
    float yp1 = tl[base + 2][r];                // y[jstart+2]
    float e1 = 0.f, e2 = 0.f;

    // uniform 128 steps; stores predicated; junk tail reads allocated slack.
    for (int t0 = 0; t0 < 128; t0 += 32) {
        #pragma unroll
        for (int tq = 0; tq < 32; tq += 8) {
            float yv[8];
            #pragma unroll
            for (int k = 0; k < 8; ++k)
                yv[k] = tl[base + 3 + t0 + tq + k][r];
            #pragma unroll
            for (int k = 0; k < 8; ++k) {
                const float y3 = yv[k];
                float tg = __builtin_fmaf(-c1, yp1, y3);
                tg = __builtin_fmaf(-p1v, yp2, tg) - m;
                const float e = __builtin_fmaf(-q1, e2,
                                  __builtin_fmaf(-q0, e1, tg));
                const int j = jstart + t0 + tq + k;
                if (j >= jsub && j < jmax)
                    tl[base + 3 + t0 + tq + k][r] = e;   // in-place (col j+3)
                e2 = e1; e1 = e; yp2 = yp1; yp1 = y3;
            }
        }
        __syncthreads();   // bound cross-wave skew (<32) under 64-col margin
    }

    // ---- dump: per row, 2 consecutive 512B stores (1KB run) ----
    const int cnt  = j1 - j0;                   // 256 (or 253 for c==15)
    const int doff = j0 + 3 - tbase;            // eps_j lives at col j+3-tbase
    #pragma unroll 4
    for (int rr = 0; rr < ROWS; ++rr) {
        float* orow = O + (size_t)rr * TOUT + j0;
        #pragma unroll
        for (int b = 0; b < 2; ++b) {
            const int u = b * 128 + tid;
            if (u < cnt) orow[u] = tl[u + doff][rr];
        }
    }

    // trailing Q zeros (harness poisons d_out)
    if (c == NCHUNK - 1 && tid < ROWS * 2) {
        O[(size_t)(tid >> 1) * TOUT + NJ + (tid & 1)] = 0.f;
    }
}

extern "C" void kernel_launch(void* const* d_in, const int* in_sizes, int n_in,
                              void* d_out, int out_size, void* d_ws, size_t ws_size,
                              hipStream_t stream) {
    const float* y     = (const float*)d_in[0];
    const float* phi   = (const float*)d_in[1];
    const float* theta = (const float*)d_in[2];
    const float* mu    = (const float*)d_in[3];
    float* out         = (float*)d_out;

    int B = in_sizes[0] / TSEQ;                 // 8192
    int rowgroups = B / ROWS;                   // 256
    dim3 block(128);
    dim3 grid(rowgroups * NCHUNK);              // 4096 two-wave blocks
    arima_eps_burst<<<grid, block, 0, stream>>>(y, phi, theta, mu, out);
}